// Round 9
// baseline (290.222 us; speedup 1.0000x reference)
//
#include <hip/hip_runtime.h>

typedef __attribute__((ext_vector_type(8))) __bf16 bf16x8;
typedef __attribute__((ext_vector_type(4))) float  f32x4;

#define DEV __device__ __forceinline__

DEV void async_copy16(const void* g, void* l) {
  __builtin_amdgcn_global_load_lds((const __attribute__((address_space(1))) void*)g,
                                   (__attribute__((address_space(3))) void*)l, 16, 0, 0);
}

// load element i of a raw input as float; isbf chooses bf16 vs fp32 interpretation
DEV float ldf(const void* p, size_t i, int isbf) {
  if (isbf) {
    unsigned int w = ((unsigned int)((const unsigned short*)p)[i]) << 16;
    float f; __builtin_memcpy(&f, &w, 4); return f;
  }
  return ((const float*)p)[i];
}

// uniform per-block dtype probe on x's first 64 halfwords (scalar loads; all lanes agree)
DEV int detect_isbf(const unsigned short* __restrict__ x) {
  int bad = 0;
#pragma unroll
  for (int i = 0; i < 64; i++) {
    int e = (x[i] >> 7) & 0xFF;
    bad |= (e >= 0x90) ? 1 : 0;
  }
  return !bad;
}

// ---- fused prep: z<4 -> transpose weight z into bf16 [C][R]; z==4 -> x cast (fp32 only) + bias ----
__global__ __launch_bounds__(256) void prep(const void* __restrict__ Wq,
                                            const void* __restrict__ Wk,
                                            const void* __restrict__ Wv,
                                            const void* __restrict__ Wo,
                                            const void* __restrict__ x,
                                            const void* __restrict__ bq,
                                            const void* __restrict__ bk,
                                            const void* __restrict__ bv,
                                            const void* __restrict__ bo,
                                            __bf16* __restrict__ Wt,
                                            __bf16* __restrict__ Wot,
                                            __bf16* __restrict__ x_bf,
                                            float* __restrict__ bias) {
  __shared__ float tile[32][33];
  const int isbf = detect_isbf((const unsigned short*)x);
  const int tid = threadIdx.x;
  const int z = blockIdx.z;

  if (z < 4) {
    const void* in = (z == 0) ? Wq : (z == 1) ? Wk : (z == 2) ? Wv : Wo;
    __bf16* out = (z < 3) ? (Wt + (size_t)z * 1024 * 1024) : Wot;
    const int tx = tid & 31, ty = tid >> 5;
    const int r0 = blockIdx.y * 32, c0 = blockIdx.x * 32;
#pragma unroll
    for (int i = 0; i < 4; i++) {
      int r = ty + i * 8;
      tile[r][tx] = ldf(in, (size_t)(r0 + r) * 1024 + c0 + tx, isbf);
    }
    __syncthreads();
#pragma unroll
    for (int i = 0; i < 4; i++) {
      int r = ty + i * 8;
      out[(size_t)(c0 + r) * 1024 + r0 + tx] = (__bf16)tile[tx][r];
    }
  } else {
    const int id = blockIdx.y * 32 + blockIdx.x;  // 0..1023
    if (!isbf) {
#pragma unroll
      for (int j = 0; j < 4; j++) {
        int idx = id * 1024 + j * 256 + tid;
        float4 f = ((const float4*)x)[idx];
        union { __bf16 h[4]; uint2 u; } pk;
        pk.h[0] = (__bf16)f.x; pk.h[1] = (__bf16)f.y;
        pk.h[2] = (__bf16)f.z; pk.h[3] = (__bf16)f.w;
        ((uint2*)x_bf)[idx] = pk.u;
      }
    }
    if (id < 16) {
      int i = id * 256 + tid;
      if (i < 1024)      bias[i] = ldf(bq, i, isbf);
      else if (i < 2048) bias[i] = ldf(bk, i - 1024, isbf);
      else if (i < 3072) bias[i] = ldf(bv, i - 2048, isbf);
      else               bias[i] = ldf(bo, i - 3072, isbf);
    }
  }
}

// ---------------- GEMM: C[M,NT-tiled] = A[M,K] @ Bt[N,K]^T + bias ----------------
template <int DYN, int NT, int ALT>
__global__ __launch_bounds__(256, 3) void gemm_bt(const __bf16* __restrict__ A,
                                                  const __bf16* __restrict__ Aalt,
                                                  const __bf16* __restrict__ Bt,
                                                  const float* __restrict__ bias,
                                                  void* __restrict__ Cout,
                                                  const unsigned short* __restrict__ xdet,
                                                  int M, int N, int K) {
  constexpr int WN = NT / 2;
  constexpr int JB = WN / 16;
  constexpr int NR = NT / 32;
  __shared__ __align__(16) __bf16 As[128 * 64];
  __shared__ __align__(16) __bf16 Bs[NT * 64];
  const int tid = threadIdx.x;
  const int wid = tid >> 6, lane = tid & 63;
  const int m_blk = blockIdx.x * 128, n_blk = blockIdx.y * NT;
  const int wm = (wid & 1) * 64, wn = (wid >> 1) * WN;
  const int l8 = lane >> 3, l7 = lane & 7;
  const int cc = l7 ^ (l8 & 7);
  const int q4 = lane >> 4, l15 = lane & 15;

  int isbf = 1;
  if (DYN || ALT) isbf = detect_isbf(xdet);
  const __bf16* Ap = (ALT && isbf) ? Aalt : A;

  f32x4 acc[4][JB] = {};

  for (int kb = 0; kb < K; kb += 64) {
    __syncthreads();
#pragma unroll
    for (int i = 0; i < 4; i++) {
      int row = i * 32 + wid * 8 + l8;
      async_copy16(Ap + (size_t)(m_blk + row) * K + kb + cc * 8,
                   As + (i * 32 + wid * 8) * 64);
    }
#pragma unroll
    for (int i = 0; i < NR; i++) {
      int row = i * 32 + wid * 8 + l8;
      async_copy16(Bt + (size_t)(n_blk + row) * K + kb + cc * 8,
                   Bs + (i * 32 + wid * 8) * 64);
    }
    __syncthreads();
#pragma unroll
    for (int k0 = 0; k0 < 64; k0 += 32) {
      bf16x8 a[4], b[JB];
#pragma unroll
      for (int i = 0; i < 4; i++) {
        int ra = wm + i * 16 + l15;
        int ba = ra * 8 + (((k0 >> 3) + q4) ^ (ra & 7));
        a[i] = *(const bf16x8*)&As[ba * 8];
      }
#pragma unroll
      for (int j = 0; j < JB; j++) {
        int rb = wn + j * 16 + l15;
        int bb = rb * 8 + (((k0 >> 3) + q4) ^ (rb & 7));
        b[j] = *(const bf16x8*)&Bs[bb * 8];
      }
#pragma unroll
      for (int i = 0; i < 4; i++)
#pragma unroll
        for (int j = 0; j < JB; j++)
          acc[i][j] = __builtin_amdgcn_mfma_f32_16x16x32_bf16(a[i], b[j], acc[i][j], 0, 0, 0);
    }
  }

  float bcol[JB];
#pragma unroll
  for (int j = 0; j < JB; j++) bcol[j] = bias[n_blk + wn + j * 16 + l15];
#pragma unroll
  for (int i = 0; i < 4; i++)
#pragma unroll
    for (int j = 0; j < JB; j++) {
      int col = n_blk + wn + j * 16 + l15;
#pragma unroll
      for (int r = 0; r < 4; r++) {
        int row = m_blk + wm + i * 16 + q4 * 4 + r;
        float v = acc[i][j][r] + bcol[j];
        size_t idx = (size_t)row * N + col;
        if (DYN && !isbf) ((float*)Cout)[idx] = v;
        else              ((__bf16*)Cout)[idx] = (__bf16)v;
      }
    }
}

// ---------------- LN + RoPE + V-transpose (fused) ----------------
__global__ __launch_bounds__(256) void ln_rope_v(const __bf16* __restrict__ qkv,
                                                 const void* __restrict__ rcos,
                                                 const void* __restrict__ rsin,
                                                 const void* __restrict__ qw,
                                                 const void* __restrict__ qb,
                                                 const void* __restrict__ kw,
                                                 const void* __restrict__ kb_,
                                                 const unsigned short* __restrict__ xdet,
                                                 __bf16* __restrict__ Qp,
                                                 __bf16* __restrict__ Kp,
                                                 __bf16* __restrict__ Vt) {
  __shared__ __bf16 vt[64][68];
  const int isbf = detect_isbf(xdet);
  const int tid = threadIdx.x, w = tid >> 6, lane = tid & 63;
  const int bh = blockIdx.y, h = bh & 15, b = bh >> 4;
  const int n0 = blockIdx.x * 64;

  float gq = ldf(qw, lane, isbf), bq_ = ldf(qb, lane, isbf);
  float gk = ldf(kw, lane, isbf), bk_ = ldf(kb_, lane, isbf);

  for (int t = 0; t < 16; t++) {
    const int n = n0 + w * 16 + t;
    const size_t tok = (size_t)b * 2048 + n;
    const __bf16* base = qkv + tok * 3072 + h * 192;
    float qv = (float)base[lane], kv = (float)base[64 + lane], vv = (float)base[128 + lane];

    float sq = qv, sk = kv;
#pragma unroll
    for (int m = 1; m < 64; m <<= 1) { sq += __shfl_xor(sq, m, 64); sk += __shfl_xor(sk, m, 64); }
    float muq = sq * (1.0f / 64.0f), muk = sk * (1.0f / 64.0f);
    float tq = qv - muq, tk = kv - muk;
    float vq = tq * tq, vk = tk * tk;
#pragma unroll
    for (int m = 1; m < 64; m <<= 1) { vq += __shfl_xor(vq, m, 64); vk += __shfl_xor(vk, m, 64); }
    float rsq = rsqrtf(vq * (1.0f / 64.0f) + 1e-6f);
    float rsk = rsqrtf(vk * (1.0f / 64.0f) + 1e-6f);
    float qn = tq * rsq * gq + bq_;
    float kn = tk * rsk * gk + bk_;

    float c = ldf(rcos, tok * 64 + lane, isbf), s = ldf(rsin, tok * 64 + lane, isbf);
    float qpart = __shfl_xor(qn, 32, 64), kpart = __shfl_xor(kn, 32, 64);
    float qrh = (lane < 32) ? -qpart : qpart;
    float krh = (lane < 32) ? -kpart : kpart;

    const size_t oidx = ((size_t)bh * 2048 + n) * 64 + lane;
    Qp[oidx] = (__bf16)((qn * c + qrh * s) * 0.1803368801111204f);  // 0.125 * log2(e)
    Kp[oidx] = (__bf16)(kn * c + krh * s);
    vt[lane][w * 16 + t] = (__bf16)vv;
  }
  __syncthreads();
  const int row = tid >> 2, qt = tid & 3;
  size_t gbase = (size_t)bh * 64 * 2048 + (size_t)row * 2048 + n0 + qt * 16;
#pragma unroll
  for (int u = 0; u < 4; u++)
    *(uint2*)&Vt[gbase + u * 4] = *(const uint2*)&vt[row][qt * 16 + u * 4];
}

// ---------------- flash attention: K-split x3, KT=32, fully co-resident ----------------
// grid (16,32,3) = 1536 blocks = EXACTLY 6 blocks/CU x 256 CUs (LDS 24KB x 6 = 144KB),
// __launch_bounds__(256,6), VGPR 52 < 64 -> 24 waves/CU co-resident, single dispatch
// wave, no tail. Splits cover 22/21/21 iterations of 32 keys. Partial O stored bf16
// (rel err 2^-9, ~1e-4 on final output); l via ones-row MFMA.
__global__ __launch_bounds__(256, 6) void attn(const __bf16* __restrict__ Qp,
                                               const __bf16* __restrict__ Kp,
                                               const __bf16* __restrict__ Vt,
                                               __bf16* __restrict__ Opart,
                                               float* __restrict__ lpart) {
  __shared__ __align__(16) __bf16 sK[2][2048];   // [buf][(g=ks*2+c)*64+lane]*8
  __shared__ __align__(16) __bf16 sV[2][2048];   // [buf][(ds*64+lane)]*8
  __shared__ __align__(16) __bf16 sP[4][1024];   // per-wave, B-frag order (32q x 32k)

  const int tid = threadIdx.x, wid = tid >> 6, lane = tid & 63;
  const int q4 = lane >> 4, l15 = lane & 15;
  const int bh = blockIdx.y, split = blockIdx.z;
  const int q0w = blockIdx.x * 128 + wid * 32;
  const int it0 = (split == 0) ? 0 : (22 + 21 * (split - 1));  // 0 / 22 / 43
  const int niter = (split == 0) ? 22 : 21;                    // 22+21+21 = 64 iters
  const __bf16* Qb = Qp + (size_t)bh * 2048 * 64;
  const __bf16* Kb = Kp + (size_t)bh * 2048 * 64;
  const __bf16* Vb = Vt + (size_t)bh * 64 * 2048;
  __bf16* Op = Opart + (size_t)split * 4194304;  // [32][2048][64] bf16 slabs
  __bf16* sPw = &sP[wid][0];
  const int pbase = (q4 >> 1) * 128 + l15 * 8 + (q4 & 1) * 4;

  // Q fragments (B-operand): B[q=l15][k=q4*8+j], 2 chains of 32 d
  bf16x8 qf[2][2];
#pragma unroll
  for (int qs = 0; qs < 2; qs++)
#pragma unroll
    for (int c = 0; c < 2; c++)
      qf[qs][c] = *(const bf16x8*)&Qb[(size_t)(q0w + qs * 16 + l15) * 64 + c * 32 + q4 * 8];

  // all-ones A-fragment -> l row sums on the matrix pipe
  bf16x8 ones8;
#pragma unroll
  for (int i = 0; i < 8; i++) ones8[i] = (__bf16)1.0f;

  f32x4 o[2][4] = {};
  f32x4 l_acc[2] = {};

#define STAGE(kt, bf)                                                                    \
  do {                                                                                   \
    async_copy16(Kb + (size_t)((kt) + (wid >> 1) * 16 + l15) * 64 + (wid & 1) * 32 + q4 * 8, \
                 &sK[bf][wid * 512]);                                                    \
    async_copy16(Vb + (size_t)(wid * 16 + l15) * 2048 + (kt) + q4 * 8,                   \
                 &sV[bf][wid * 512]);                                                    \
  } while (0)

  STAGE(it0 * 32, 0);

  for (int it = 0; it < niter; ++it) {
    const int buf = it & 1;
    __syncthreads();  // readers of buf^1 done + loads into buf landed
    if (it < niter - 1) STAGE((it0 + it + 1) * 32, buf ^ 1);

    // ---- QK^T (S^T): A = K rows (2 ks-subs), B = Q (2 q-subs), 2 d-chains ----
    bf16x8 ak[2][2];
#pragma unroll
    for (int ks = 0; ks < 2; ks++)
#pragma unroll
      for (int c = 0; c < 2; c++)
        ak[ks][c] = *(const bf16x8*)&sK[buf][((ks * 2 + c) * 64 + lane) * 8];
    f32x4 sc[2][2];
#pragma unroll
    for (int qs = 0; qs < 2; qs++)
#pragma unroll
      for (int ks = 0; ks < 2; ks++) {
        f32x4 z = {0.f, 0.f, 0.f, 0.f};
        z = __builtin_amdgcn_mfma_f32_16x16x32_bf16(ak[ks][0], qf[qs][0], z, 0, 0, 0);
        z = __builtin_amdgcn_mfma_f32_16x16x32_bf16(ak[ks][1], qf[qs][1], z, 0, 0, 0);
        sc[qs][ks] = z;
      }

    // ---- no-max softmax: p = exp2(s); truncate-pack to bf16 via v_perm ----
#pragma unroll
    for (int qs = 0; qs < 2; qs++)
#pragma unroll
      for (int ks = 0; ks < 2; ks++) {
        uint2 pk;
        {
          float p0 = __builtin_amdgcn_exp2f(sc[qs][ks][0]);
          float p1 = __builtin_amdgcn_exp2f(sc[qs][ks][1]);
          pk.x = __builtin_amdgcn_perm(__builtin_bit_cast(unsigned int, p1),
                                       __builtin_bit_cast(unsigned int, p0), 0x07060302u);
          float p2 = __builtin_amdgcn_exp2f(sc[qs][ks][2]);
          float p3 = __builtin_amdgcn_exp2f(sc[qs][ks][3]);
          pk.y = __builtin_amdgcn_perm(__builtin_bit_cast(unsigned int, p3),
                                       __builtin_bit_cast(unsigned int, p2), 0x07060302u);
        }
        *(uint2*)&sPw[qs * 512 + ks * 256 + pbase] = pk;
      }
    asm volatile("s_waitcnt lgkmcnt(0)" ::: "memory");  // P writes -> reads (same wave)

    // ---- PV (O^T += V^T.P) + l += ones.P on the matrix pipe ----
    bf16x8 pb[2];
#pragma unroll
    for (int qs = 0; qs < 2; qs++)
      pb[qs] = *(const bf16x8*)&sPw[(qs * 64 + lane) * 8];
#pragma unroll
    for (int qs = 0; qs < 2; qs++)
      l_acc[qs] = __builtin_amdgcn_mfma_f32_16x16x32_bf16(ones8, pb[qs], l_acc[qs], 0, 0, 0);
#pragma unroll
    for (int ds = 0; ds < 4; ds++) {
      bf16x8 av = *(const bf16x8*)&sV[buf][(ds * 64 + lane) * 8];
#pragma unroll
      for (int qs = 0; qs < 2; qs++)
        o[qs][ds] = __builtin_amdgcn_mfma_f32_16x16x32_bf16(av, pb[qs], o[qs][ds], 0, 0, 0);
    }
  }
#undef STAGE

  // ---- epilogue: bf16 partial O ([bh][q][d]) and fp32 partial l ----
#pragma unroll
  for (int qs = 0; qs < 2; qs++) {
    const int q = q0w + qs * 16 + l15;
    if (q4 == 0) lpart[(size_t)(split * 32 + bh) * 2048 + q] = l_acc[qs][0];
    size_t base = ((size_t)bh * 2048 + q) * 64;
#pragma unroll
    for (int ds = 0; ds < 4; ds++) {
      union { __bf16 h4[4]; uint2 u; } pk;
#pragma unroll
      for (int r = 0; r < 4; r++) pk.h4[r] = (__bf16)o[qs][ds][r];
      *(uint2*)&Op[base + ds * 16 + q4 * 4] = pk.u;
    }
  }
}

// ---------------- combine: Obuf = (O0+O1+O2) / (l0+l1+l2), bf16 [b][q][h*64+d] ----------------
__global__ __launch_bounds__(256) void combine(const __bf16* __restrict__ Opart,
                                               const float* __restrict__ lpart,
                                               __bf16* __restrict__ Obuf) {
  const int idx = blockIdx.x * 256 + threadIdx.x;  // 1,048,576 threads x 4 d
  const int d4 = idx & 15, q = (idx >> 4) & 2047, bh = idx >> 15;
  const int b = bh >> 4, h = bh & 15;
  const size_t po = ((size_t)bh * 2048 + q) * 64 + d4 * 4;
  float acc[4] = {0.f, 0.f, 0.f, 0.f};
#pragma unroll
  for (int s = 0; s < 3; s++) {
    union { __bf16 h4[4]; uint2 u; } pk;
    pk.u = *(const uint2*)&Opart[(size_t)s * 4194304 + po];
#pragma unroll
    for (int r = 0; r < 4; r++) acc[r] += (float)pk.h4[r];
  }
  float l = lpart[(size_t)bh * 2048 + q] + lpart[(size_t)(32 + bh) * 2048 + q] +
            lpart[(size_t)(64 + bh) * 2048 + q];
  float rl = 1.0f / l;
  union { __bf16 h4[4]; uint2 u; } out;
#pragma unroll
  for (int r = 0; r < 4; r++) out.h4[r] = (__bf16)(acc[r] * rl);
  *(uint2*)&Obuf[((size_t)(b * 2048 + q)) * 1024 + h * 64 + d4 * 4] = out.u;
}

extern "C" void kernel_launch(void* const* d_in, const int* in_sizes, int n_in,
                              void* d_out, int out_size, void* d_ws, size_t ws_size,
                              hipStream_t stream) {
  const void* x   = d_in[0];
  const void* rc  = d_in[1];
  const void* rs  = d_in[2];
  const void* Wq  = d_in[3];
  const void* bq  = d_in[4];
  const void* Wk  = d_in[5];
  const void* bk  = d_in[6];
  const void* Wv  = d_in[7];
  const void* bv  = d_in[8];
  const void* qnw = d_in[9];
  const void* qnb = d_in[10];
  const void* knw = d_in[11];
  const void* knb = d_in[12];
  const void* Wo  = d_in[13];
  const void* bo  = d_in[14];
  const unsigned short* xdet = (const unsigned short*)x;

  // temporal aliasing plan:
  //  [0, 25165824)        qkv bf16 (gemm0 -> ln_rope_v), then Opart bf16 [3][8MB] (attn -> combine)
  //  [25165824, 33554432) x_bf (prep -> gemm0, fp32 path only)
  //  [33554432, 41943040) Qp, then Obuf (combine -> gemm1; Qp dead after attn)
  char* ws = (char*)d_ws;
  __bf16* qkv   = (__bf16*)ws;
  __bf16* Opart = (__bf16*)ws;
  __bf16* x_bf  = (__bf16*)(ws + 25165824);
  __bf16* Qp    = (__bf16*)(ws + 33554432);
  __bf16* Obuf  = (__bf16*)(ws + 33554432);
  __bf16* Kp    = (__bf16*)(ws + 41943040);
  __bf16* Vt    = (__bf16*)(ws + 50331648);
  __bf16* Wt    = (__bf16*)(ws + 58720256);   // [3072][1024] 6 MB
  __bf16* Wot   = (__bf16*)(ws + 65011712);   // [1024][1024] 2 MB
  float*  bias  = (float*)(ws + 67108864);    // [4096]
  float*  lprt  = (float*)(ws + 67125248);    // [3][32][2048] fp32, 768 KB

  prep<<<dim3(32, 32, 5), 256, 0, stream>>>(Wq, Wk, Wv, Wo, x, bq, bk, bv, bo,
                                            Wt, Wot, x_bf, bias);
  gemm_bt<0, 128, 1><<<dim3(32, 24), 256, 0, stream>>>(x_bf, (const __bf16*)x, Wt, bias,
                                                       qkv, xdet, 4096, 3072, 1024);
  ln_rope_v<<<dim3(32, 32), 256, 0, stream>>>(qkv, rc, rs, qnw, qnb, knw, knb, xdet,
                                              Qp, Kp, Vt);
  attn<<<dim3(16, 32, 3), 256, 0, stream>>>(Qp, Kp, Vt, Opart, lprt);
  combine<<<4096, 256, 0, stream>>>(Opart, lprt, Obuf);
  gemm_bt<1, 64, 0><<<dim3(32, 16), 256, 0, stream>>>(Obuf, nullptr, Wot, bias + 3072,
                                                      d_out, xdet, 4096, 1024, 1024);
}

// Round 10
// 260.990 us; speedup vs baseline: 1.1120x; 1.1120x over previous
//
#include <hip/hip_runtime.h>

typedef __attribute__((ext_vector_type(8))) __bf16 bf16x8;
typedef __attribute__((ext_vector_type(4))) float  f32x4;

#define DEV __device__ __forceinline__

DEV void async_copy16(const void* g, void* l) {
  __builtin_amdgcn_global_load_lds((const __attribute__((address_space(1))) void*)g,
                                   (__attribute__((address_space(3))) void*)l, 16, 0, 0);
}

// load element i of a raw input as float; isbf chooses bf16 vs fp32 interpretation
DEV float ldf(const void* p, size_t i, int isbf) {
  if (isbf) {
    unsigned int w = ((unsigned int)((const unsigned short*)p)[i]) << 16;
    float f; __builtin_memcpy(&f, &w, 4); return f;
  }
  return ((const float*)p)[i];
}

// uniform per-block dtype probe on x's first 64 halfwords (scalar loads; all lanes agree)
DEV int detect_isbf(const unsigned short* __restrict__ x) {
  int bad = 0;
#pragma unroll
  for (int i = 0; i < 64; i++) {
    int e = (x[i] >> 7) & 0xFF;
    bad |= (e >= 0x90) ? 1 : 0;
  }
  return !bad;
}

// ---- fused prep: z<4 -> transpose weight z into bf16 [C][R]; z==4 -> x cast (fp32 only) + bias ----
__global__ __launch_bounds__(256) void prep(const void* __restrict__ Wq,
                                            const void* __restrict__ Wk,
                                            const void* __restrict__ Wv,
                                            const void* __restrict__ Wo,
                                            const void* __restrict__ x,
                                            const void* __restrict__ bq,
                                            const void* __restrict__ bk,
                                            const void* __restrict__ bv,
                                            const void* __restrict__ bo,
                                            __bf16* __restrict__ Wt,
                                            __bf16* __restrict__ Wot,
                                            __bf16* __restrict__ x_bf,
                                            float* __restrict__ bias) {
  __shared__ float tile[32][33];
  const int isbf = detect_isbf((const unsigned short*)x);
  const int tid = threadIdx.x;
  const int z = blockIdx.z;

  if (z < 4) {
    const void* in = (z == 0) ? Wq : (z == 1) ? Wk : (z == 2) ? Wv : Wo;
    __bf16* out = (z < 3) ? (Wt + (size_t)z * 1024 * 1024) : Wot;
    const int tx = tid & 31, ty = tid >> 5;
    const int r0 = blockIdx.y * 32, c0 = blockIdx.x * 32;
#pragma unroll
    for (int i = 0; i < 4; i++) {
      int r = ty + i * 8;
      tile[r][tx] = ldf(in, (size_t)(r0 + r) * 1024 + c0 + tx, isbf);
    }
    __syncthreads();
#pragma unroll
    for (int i = 0; i < 4; i++) {
      int r = ty + i * 8;
      out[(size_t)(c0 + r) * 1024 + r0 + tx] = (__bf16)tile[tx][r];
    }
  } else {
    const int id = blockIdx.y * 32 + blockIdx.x;  // 0..1023
    if (!isbf) {
#pragma unroll
      for (int j = 0; j < 4; j++) {
        int idx = id * 1024 + j * 256 + tid;
        float4 f = ((const float4*)x)[idx];
        union { __bf16 h[4]; uint2 u; } pk;
        pk.h[0] = (__bf16)f.x; pk.h[1] = (__bf16)f.y;
        pk.h[2] = (__bf16)f.z; pk.h[3] = (__bf16)f.w;
        ((uint2*)x_bf)[idx] = pk.u;
      }
    }
    if (id < 16) {
      int i = id * 256 + tid;
      if (i < 1024)      bias[i] = ldf(bq, i, isbf);
      else if (i < 2048) bias[i] = ldf(bk, i - 1024, isbf);
      else if (i < 3072) bias[i] = ldf(bv, i - 2048, isbf);
      else               bias[i] = ldf(bo, i - 3072, isbf);
    }
  }
}

// ---------------- GEMM: C[M,NT-tiled] = A[M,K] @ Bt[N,K]^T + bias ----------------
// MODE 0: A from A ptr. MODE 1: A from Aalt (raw x) when input is bf16.
// MODE 2: A = (O0+O1)/l combined on the fly during staging (fused attention combine):
//         A ptr = O0 (fp32 [32][2048][64]), Aalt = O1, lp = lpart [2][32][2048].
template <int DYN, int NT, int MODE>
__global__ __launch_bounds__(256, 3) void gemm_bt(const void* __restrict__ A,
                                                  const void* __restrict__ Aalt,
                                                  const __bf16* __restrict__ Bt,
                                                  const float* __restrict__ bias,
                                                  void* __restrict__ Cout,
                                                  const unsigned short* __restrict__ xdet,
                                                  const float* __restrict__ lp,
                                                  int M, int N, int K) {
  constexpr int WN = NT / 2;
  constexpr int JB = WN / 16;
  constexpr int NR = NT / 32;
  __shared__ __align__(16) __bf16 As[128 * 64];
  __shared__ __align__(16) __bf16 Bs[NT * 64];
  const int tid = threadIdx.x;
  const int wid = tid >> 6, lane = tid & 63;
  const int m_blk = blockIdx.x * 128, n_blk = blockIdx.y * NT;
  const int wm = (wid & 1) * 64, wn = (wid >> 1) * WN;
  const int l8 = lane >> 3, l7 = lane & 7;
  const int cc = l7 ^ (l8 & 7);
  const int q4 = lane >> 4, l15 = lane & 15;

  int isbf = 1;
  if (DYN || MODE == 1) isbf = detect_isbf(xdet);
  const __bf16* Ap = (MODE == 1 && isbf) ? (const __bf16*)Aalt : (const __bf16*)A;

  f32x4 acc[4][JB] = {};

  for (int kb = 0; kb < K; kb += 64) {
    __syncthreads();
    if (MODE == 2) {
      // A[m][kb+cc*8 .. +7]: h = kb>>6 (K-step 64 == head width), d = cc*8
      const float* O0f = (const float*)A;
      const float* O1f = (const float*)Aalt;
      const int h = kb >> 6;
#pragma unroll
      for (int i = 0; i < 4; i++) {
        int row = i * 32 + wid * 8 + l8;
        int m = m_blk + row;
        int b = m >> 11, qloc = m & 2047;
        size_t bhq = (size_t)(b * 16 + h) * 2048 + qloc;
        size_t po = bhq * 64 + cc * 8;
        f32x4 a0 = *(const f32x4*)&O0f[po];
        f32x4 a1 = *(const f32x4*)&O0f[po + 4];
        f32x4 c0 = *(const f32x4*)&O1f[po];
        f32x4 c1 = *(const f32x4*)&O1f[po + 4];
        float rl = 1.0f / (lp[bhq] + lp[bhq + 32 * 2048]);
        union { __bf16 h8[8]; uint4 u; } pk;
#pragma unroll
        for (int r = 0; r < 4; r++) {
          pk.h8[r]     = (__bf16)((a0[r] + c0[r]) * rl);
          pk.h8[4 + r] = (__bf16)((a1[r] + c1[r]) * rl);
        }
        *(uint4*)&As[row * 64 + l7 * 8] = pk.u;
      }
    } else {
#pragma unroll
      for (int i = 0; i < 4; i++) {
        int row = i * 32 + wid * 8 + l8;
        async_copy16(Ap + (size_t)(m_blk + row) * K + kb + cc * 8,
                     As + (i * 32 + wid * 8) * 64);
      }
    }
#pragma unroll
    for (int i = 0; i < NR; i++) {
      int row = i * 32 + wid * 8 + l8;
      async_copy16(Bt + (size_t)(n_blk + row) * K + kb + cc * 8,
                   Bs + (i * 32 + wid * 8) * 64);
    }
    __syncthreads();
#pragma unroll
    for (int k0 = 0; k0 < 64; k0 += 32) {
      bf16x8 a[4], b[JB];
#pragma unroll
      for (int i = 0; i < 4; i++) {
        int ra = wm + i * 16 + l15;
        int ba = ra * 8 + (((k0 >> 3) + q4) ^ (ra & 7));
        a[i] = *(const bf16x8*)&As[ba * 8];
      }
#pragma unroll
      for (int j = 0; j < JB; j++) {
        int rb = wn + j * 16 + l15;
        int bb = rb * 8 + (((k0 >> 3) + q4) ^ (rb & 7));
        b[j] = *(const bf16x8*)&Bs[bb * 8];
      }
#pragma unroll
      for (int i = 0; i < 4; i++)
#pragma unroll
        for (int j = 0; j < JB; j++)
          acc[i][j] = __builtin_amdgcn_mfma_f32_16x16x32_bf16(a[i], b[j], acc[i][j], 0, 0, 0);
    }
  }

  float bcol[JB];
#pragma unroll
  for (int j = 0; j < JB; j++) bcol[j] = bias[n_blk + wn + j * 16 + l15];
#pragma unroll
  for (int i = 0; i < 4; i++)
#pragma unroll
    for (int j = 0; j < JB; j++) {
      int col = n_blk + wn + j * 16 + l15;
#pragma unroll
      for (int r = 0; r < 4; r++) {
        int row = m_blk + wm + i * 16 + q4 * 4 + r;
        float v = acc[i][j][r] + bcol[j];
        size_t idx = (size_t)row * N + col;
        if (DYN && !isbf) ((float*)Cout)[idx] = v;
        else              ((__bf16*)Cout)[idx] = (__bf16)v;
      }
    }
}

// ---------------- LN + RoPE + V-transpose (fused) ----------------
__global__ __launch_bounds__(256) void ln_rope_v(const __bf16* __restrict__ qkv,
                                                 const void* __restrict__ rcos,
                                                 const void* __restrict__ rsin,
                                                 const void* __restrict__ qw,
                                                 const void* __restrict__ qb,
                                                 const void* __restrict__ kw,
                                                 const void* __restrict__ kb_,
                                                 const unsigned short* __restrict__ xdet,
                                                 __bf16* __restrict__ Qp,
                                                 __bf16* __restrict__ Kp,
                                                 __bf16* __restrict__ Vt) {
  __shared__ __bf16 vt[64][68];
  const int isbf = detect_isbf(xdet);
  const int tid = threadIdx.x, w = tid >> 6, lane = tid & 63;
  const int bh = blockIdx.y, h = bh & 15, b = bh >> 4;
  const int n0 = blockIdx.x * 64;

  float gq = ldf(qw, lane, isbf), bq_ = ldf(qb, lane, isbf);
  float gk = ldf(kw, lane, isbf), bk_ = ldf(kb_, lane, isbf);

#pragma unroll 2
  for (int t = 0; t < 16; t++) {
    const int n = n0 + w * 16 + t;
    const size_t tok = (size_t)b * 2048 + n;
    const __bf16* base = qkv + tok * 3072 + h * 192;
    float qv = (float)base[lane], kv = (float)base[64 + lane], vv = (float)base[128 + lane];

    float sq = qv, sk = kv;
#pragma unroll
    for (int m = 1; m < 64; m <<= 1) { sq += __shfl_xor(sq, m, 64); sk += __shfl_xor(sk, m, 64); }
    float muq = sq * (1.0f / 64.0f), muk = sk * (1.0f / 64.0f);
    float tq = qv - muq, tk = kv - muk;
    float vq = tq * tq, vk = tk * tk;
#pragma unroll
    for (int m = 1; m < 64; m <<= 1) { vq += __shfl_xor(vq, m, 64); vk += __shfl_xor(vk, m, 64); }
    float rsq = rsqrtf(vq * (1.0f / 64.0f) + 1e-6f);
    float rsk = rsqrtf(vk * (1.0f / 64.0f) + 1e-6f);
    float qn = tq * rsq * gq + bq_;
    float kn = tk * rsk * gk + bk_;

    float c = ldf(rcos, tok * 64 + lane, isbf), s = ldf(rsin, tok * 64 + lane, isbf);
    float qpart = __shfl_xor(qn, 32, 64), kpart = __shfl_xor(kn, 32, 64);
    float qrh = (lane < 32) ? -qpart : qpart;
    float krh = (lane < 32) ? -kpart : kpart;

    const size_t oidx = ((size_t)bh * 2048 + n) * 64 + lane;
    Qp[oidx] = (__bf16)((qn * c + qrh * s) * 0.1803368801111204f);  // 0.125 * log2(e)
    Kp[oidx] = (__bf16)(kn * c + krh * s);
    vt[lane][w * 16 + t] = (__bf16)vv;
  }
  __syncthreads();
  const int row = tid >> 2, qt = tid & 3;
  size_t gbase = (size_t)bh * 64 * 2048 + (size_t)row * 2048 + n0 + qt * 16;
#pragma unroll
  for (int u = 0; u < 4; u++)
    *(uint2*)&Vt[gbase + u * 4] = *(const uint2*)&vt[row][qt * 16 + u * 4];
}

// ---------------- flash attention: K-split x2, KT=32 (round-8 proven config) ----------------
// grid (16,32,2) = 1024 blocks, 4 blocks/CU; fp32 partial O (full-line-combining 16B
// stores); l via ones-row MFMA on the matrix pipe; no-max softmax (bounded post-LN
// scores); P truncate-packed via v_perm; P in B-frag order -> conflict-free b128.
__global__ __launch_bounds__(256, 4) void attn(const __bf16* __restrict__ Qp,
                                               const __bf16* __restrict__ Kp,
                                               const __bf16* __restrict__ Vt,
                                               float* __restrict__ O0,
                                               float* __restrict__ O1,
                                               float* __restrict__ lpart) {
  __shared__ __align__(16) __bf16 sK[2][2048];   // [buf][(g=ks*2+c)*64+lane]*8
  __shared__ __align__(16) __bf16 sV[2][2048];   // [buf][(ds*64+lane)]*8
  __shared__ __align__(16) __bf16 sP[4][1024];   // per-wave, B-frag order (32q x 32k)

  const int tid = threadIdx.x, wid = tid >> 6, lane = tid & 63;
  const int q4 = lane >> 4, l15 = lane & 15;
  const int bh = blockIdx.y, split = blockIdx.z;
  const int q0w = blockIdx.x * 128 + wid * 32;
  const int kt0 = split * 1024;
  const __bf16* Qb = Qp + (size_t)bh * 2048 * 64;
  const __bf16* Kb = Kp + (size_t)bh * 2048 * 64;
  const __bf16* Vb = Vt + (size_t)bh * 64 * 2048;
  float* Op = split ? O1 : O0;
  __bf16* sPw = &sP[wid][0];
  const int pbase = (q4 >> 1) * 128 + l15 * 8 + (q4 & 1) * 4;

  // Q fragments (B-operand): B[q=l15][k=q4*8+j], 2 chains of 32 d
  bf16x8 qf[2][2];
#pragma unroll
  for (int qs = 0; qs < 2; qs++)
#pragma unroll
    for (int c = 0; c < 2; c++)
      qf[qs][c] = *(const bf16x8*)&Qb[(size_t)(q0w + qs * 16 + l15) * 64 + c * 32 + q4 * 8];

  // all-ones A-fragment -> l row sums on the matrix pipe
  bf16x8 ones8;
#pragma unroll
  for (int i = 0; i < 8; i++) ones8[i] = (__bf16)1.0f;

  f32x4 o[2][4] = {};
  f32x4 l_acc[2] = {};

#define STAGE(kt, bf)                                                                    \
  do {                                                                                   \
    async_copy16(Kb + (size_t)((kt) + (wid >> 1) * 16 + l15) * 64 + (wid & 1) * 32 + q4 * 8, \
                 &sK[bf][wid * 512]);                                                    \
    async_copy16(Vb + (size_t)(wid * 16 + l15) * 2048 + (kt) + q4 * 8,                   \
                 &sV[bf][wid * 512]);                                                    \
  } while (0)

  STAGE(kt0, 0);

  for (int it = 0; it < 32; ++it) {
    const int buf = it & 1;
    __syncthreads();  // readers of buf^1 done + loads into buf landed
    if (it < 31) STAGE(kt0 + (it + 1) * 32, buf ^ 1);

    // ---- QK^T (S^T): A = K rows (2 ks-subs), B = Q (2 q-subs), 2 d-chains ----
    bf16x8 ak[2][2];
#pragma unroll
    for (int ks = 0; ks < 2; ks++)
#pragma unroll
      for (int c = 0; c < 2; c++)
        ak[ks][c] = *(const bf16x8*)&sK[buf][((ks * 2 + c) * 64 + lane) * 8];
    f32x4 sc[2][2];
#pragma unroll
    for (int qs = 0; qs < 2; qs++)
#pragma unroll
      for (int ks = 0; ks < 2; ks++) {
        f32x4 z = {0.f, 0.f, 0.f, 0.f};
        z = __builtin_amdgcn_mfma_f32_16x16x32_bf16(ak[ks][0], qf[qs][0], z, 0, 0, 0);
        z = __builtin_amdgcn_mfma_f32_16x16x32_bf16(ak[ks][1], qf[qs][1], z, 0, 0, 0);
        sc[qs][ks] = z;
      }

    // ---- no-max softmax: p = exp2(s); truncate-pack to bf16 via v_perm ----
#pragma unroll
    for (int qs = 0; qs < 2; qs++)
#pragma unroll
      for (int ks = 0; ks < 2; ks++) {
        uint2 pk;
        {
          float p0 = __builtin_amdgcn_exp2f(sc[qs][ks][0]);
          float p1 = __builtin_amdgcn_exp2f(sc[qs][ks][1]);
          pk.x = __builtin_amdgcn_perm(__builtin_bit_cast(unsigned int, p1),
                                       __builtin_bit_cast(unsigned int, p0), 0x07060302u);
          float p2 = __builtin_amdgcn_exp2f(sc[qs][ks][2]);
          float p3 = __builtin_amdgcn_exp2f(sc[qs][ks][3]);
          pk.y = __builtin_amdgcn_perm(__builtin_bit_cast(unsigned int, p3),
                                       __builtin_bit_cast(unsigned int, p2), 0x07060302u);
        }
        *(uint2*)&sPw[qs * 512 + ks * 256 + pbase] = pk;
      }
    asm volatile("s_waitcnt lgkmcnt(0)" ::: "memory");  // P writes -> reads (same wave)

    // ---- PV (O^T += V^T.P) + l += ones.P on the matrix pipe ----
    bf16x8 pb[2];
#pragma unroll
    for (int qs = 0; qs < 2; qs++)
      pb[qs] = *(const bf16x8*)&sPw[(qs * 64 + lane) * 8];
#pragma unroll
    for (int qs = 0; qs < 2; qs++)
      l_acc[qs] = __builtin_amdgcn_mfma_f32_16x16x32_bf16(ones8, pb[qs], l_acc[qs], 0, 0, 0);
#pragma unroll
    for (int ds = 0; ds < 4; ds++) {
      bf16x8 av = *(const bf16x8*)&sV[buf][(ds * 64 + lane) * 8];
#pragma unroll
      for (int qs = 0; qs < 2; qs++)
        o[qs][ds] = __builtin_amdgcn_mfma_f32_16x16x32_bf16(av, pb[qs], o[qs][ds], 0, 0, 0);
    }
  }
#undef STAGE

  // ---- epilogue: fp32 partial O ([bh][q][d]) and fp32 partial l ----
#pragma unroll
  for (int qs = 0; qs < 2; qs++) {
    const int q = q0w + qs * 16 + l15;
    if (q4 == 0) lpart[(size_t)(split * 32 + bh) * 2048 + q] = l_acc[qs][0];
    size_t base = ((size_t)bh * 2048 + q) * 64;
#pragma unroll
    for (int ds = 0; ds < 4; ds++)
      *(f32x4*)&Op[base + ds * 16 + q4 * 4] = o[qs][ds];
  }
}

extern "C" void kernel_launch(void* const* d_in, const int* in_sizes, int n_in,
                              void* d_out, int out_size, void* d_ws, size_t ws_size,
                              hipStream_t stream) {
  const void* x   = d_in[0];
  const void* rc  = d_in[1];
  const void* rs  = d_in[2];
  const void* Wq  = d_in[3];
  const void* bq  = d_in[4];
  const void* Wk  = d_in[5];
  const void* bk  = d_in[6];
  const void* Wv  = d_in[7];
  const void* bv  = d_in[8];
  const void* qnw = d_in[9];
  const void* qnb = d_in[10];
  const void* knw = d_in[11];
  const void* knb = d_in[12];
  const void* Wo  = d_in[13];
  const void* bo  = d_in[14];
  const unsigned short* xdet = (const unsigned short*)x;

  // temporal aliasing plan:
  //  [0, 25165824)        qkv bf16 (gemm0 -> ln_rope_v), then O0/O1 fp32 (attn -> gemm1)
  //  [25165824, 33554432) x_bf (prep -> gemm0, fp32 path only); O1 tail overlaps after x_bf dead
  //  [33554432, 41943040) Qp (ln_rope_v -> attn)
  char* ws = (char*)d_ws;
  __bf16* qkv   = (__bf16*)ws;
  float*  O0    = (float*)ws;                 // 16 MB
  float*  O1    = (float*)(ws + 16777216);    // 16 MB (qkv/x_bf dead by attn)
  __bf16* x_bf  = (__bf16*)(ws + 25165824);
  __bf16* Qp    = (__bf16*)(ws + 33554432);
  __bf16* Kp    = (__bf16*)(ws + 41943040);
  __bf16* Vt    = (__bf16*)(ws + 50331648);
  __bf16* Wt    = (__bf16*)(ws + 58720256);   // [3072][1024] 6 MB
  __bf16* Wot   = (__bf16*)(ws + 65011712);   // [1024][1024] 2 MB
  float*  bias  = (float*)(ws + 67108864);    // [4096]
  float*  lprt  = (float*)(ws + 67125248);    // [2][32][2048] fp32, 512 KB

  prep<<<dim3(32, 32, 5), 256, 0, stream>>>(Wq, Wk, Wv, Wo, x, bq, bk, bv, bo,
                                            Wt, Wot, x_bf, bias);
  gemm_bt<0, 128, 1><<<dim3(32, 24), 256, 0, stream>>>(x_bf, x, Wt, bias,
                                                       qkv, xdet, nullptr, 4096, 3072, 1024);
  ln_rope_v<<<dim3(32, 32), 256, 0, stream>>>(qkv, rc, rs, qnw, qnb, knw, knb, xdet,
                                              Qp, Kp, Vt);
  attn<<<dim3(16, 32, 2), 256, 0, stream>>>(Qp, Kp, Vt, O0, O1, lprt);
  gemm_bt<1, 64, 2><<<dim3(32, 16), 256, 0, stream>>>(O0, O1, Wot, bias + 3072,
                                                      d_out, xdet, lprt, 4096, 1024, 1024);
}

// Round 11
// 235.440 us; speedup vs baseline: 1.2327x; 1.1085x over previous
//
#include <hip/hip_runtime.h>

typedef __attribute__((ext_vector_type(8))) __bf16 bf16x8;
typedef __attribute__((ext_vector_type(4))) float  f32x4;

#define DEV __device__ __forceinline__

DEV void async_copy16(const void* g, void* l) {
  __builtin_amdgcn_global_load_lds((const __attribute__((address_space(1))) void*)g,
                                   (__attribute__((address_space(3))) void*)l, 16, 0, 0);
}

// load element i of a raw input as float; isbf chooses bf16 vs fp32 interpretation
DEV float ldf(const void* p, size_t i, int isbf) {
  if (isbf) {
    unsigned int w = ((unsigned int)((const unsigned short*)p)[i]) << 16;
    float f; __builtin_memcpy(&f, &w, 4); return f;
  }
  return ((const float*)p)[i];
}

// uniform per-block dtype probe on x's first 64 halfwords (scalar loads; all lanes agree)
DEV int detect_isbf(const unsigned short* __restrict__ x) {
  int bad = 0;
#pragma unroll
  for (int i = 0; i < 64; i++) {
    int e = (x[i] >> 7) & 0xFF;
    bad |= (e >= 0x90) ? 1 : 0;
  }
  return !bad;
}

// ---- fused prep: z<4 -> transpose weight z into bf16 [C][R]; z==4 -> x cast (fp32 only) + bias ----
__global__ __launch_bounds__(256) void prep(const void* __restrict__ Wq,
                                            const void* __restrict__ Wk,
                                            const void* __restrict__ Wv,
                                            const void* __restrict__ Wo,
                                            const void* __restrict__ x,
                                            const void* __restrict__ bq,
                                            const void* __restrict__ bk,
                                            const void* __restrict__ bv,
                                            const void* __restrict__ bo,
                                            __bf16* __restrict__ Wt,
                                            __bf16* __restrict__ Wot,
                                            __bf16* __restrict__ x_bf,
                                            float* __restrict__ bias) {
  __shared__ float tile[32][33];
  const int isbf = detect_isbf((const unsigned short*)x);
  const int tid = threadIdx.x;
  const int z = blockIdx.z;

  if (z < 4) {
    const void* in = (z == 0) ? Wq : (z == 1) ? Wk : (z == 2) ? Wv : Wo;
    __bf16* out = (z < 3) ? (Wt + (size_t)z * 1024 * 1024) : Wot;
    const int tx = tid & 31, ty = tid >> 5;
    const int r0 = blockIdx.y * 32, c0 = blockIdx.x * 32;
#pragma unroll
    for (int i = 0; i < 4; i++) {
      int r = ty + i * 8;
      tile[r][tx] = ldf(in, (size_t)(r0 + r) * 1024 + c0 + tx, isbf);
    }
    __syncthreads();
#pragma unroll
    for (int i = 0; i < 4; i++) {
      int r = ty + i * 8;
      out[(size_t)(c0 + r) * 1024 + r0 + tx] = (__bf16)tile[tx][r];
    }
  } else {
    const int id = blockIdx.y * 32 + blockIdx.x;  // 0..1023
    if (!isbf) {
#pragma unroll
      for (int j = 0; j < 4; j++) {
        int idx = id * 1024 + j * 256 + tid;
        float4 f = ((const float4*)x)[idx];
        union { __bf16 h[4]; uint2 u; } pk;
        pk.h[0] = (__bf16)f.x; pk.h[1] = (__bf16)f.y;
        pk.h[2] = (__bf16)f.z; pk.h[3] = (__bf16)f.w;
        ((uint2*)x_bf)[idx] = pk.u;
      }
    }
    if (id < 16) {
      int i = id * 256 + tid;
      if (i < 1024)      bias[i] = ldf(bq, i, isbf);
      else if (i < 2048) bias[i] = ldf(bk, i - 1024, isbf);
      else if (i < 3072) bias[i] = ldf(bv, i - 2048, isbf);
      else               bias[i] = ldf(bo, i - 3072, isbf);
    }
  }
}

// ---------------- GEMM: C[M,NT-tiled] = A[M,K] @ Bt[N,K]^T + bias ----------------
// ALT=1: read A from Aalt (raw input x) when input is bf16.
template <int DYN, int NT, int ALT>
__global__ __launch_bounds__(256, 3) void gemm_bt(const __bf16* __restrict__ A,
                                                  const __bf16* __restrict__ Aalt,
                                                  const __bf16* __restrict__ Bt,
                                                  const float* __restrict__ bias,
                                                  void* __restrict__ Cout,
                                                  const unsigned short* __restrict__ xdet,
                                                  int M, int N, int K) {
  constexpr int WN = NT / 2;
  constexpr int JB = WN / 16;
  constexpr int NR = NT / 32;
  __shared__ __align__(16) __bf16 As[128 * 64];
  __shared__ __align__(16) __bf16 Bs[NT * 64];
  const int tid = threadIdx.x;
  const int wid = tid >> 6, lane = tid & 63;
  const int m_blk = blockIdx.x * 128, n_blk = blockIdx.y * NT;
  const int wm = (wid & 1) * 64, wn = (wid >> 1) * WN;
  const int l8 = lane >> 3, l7 = lane & 7;
  const int cc = l7 ^ (l8 & 7);
  const int q4 = lane >> 4, l15 = lane & 15;

  int isbf = 1;
  if (DYN || ALT) isbf = detect_isbf(xdet);
  const __bf16* Ap = (ALT && isbf) ? Aalt : A;

  f32x4 acc[4][JB] = {};

  for (int kb = 0; kb < K; kb += 64) {
    __syncthreads();
#pragma unroll
    for (int i = 0; i < 4; i++) {
      int row = i * 32 + wid * 8 + l8;
      async_copy16(Ap + (size_t)(m_blk + row) * K + kb + cc * 8,
                   As + (i * 32 + wid * 8) * 64);
    }
#pragma unroll
    for (int i = 0; i < NR; i++) {
      int row = i * 32 + wid * 8 + l8;
      async_copy16(Bt + (size_t)(n_blk + row) * K + kb + cc * 8,
                   Bs + (i * 32 + wid * 8) * 64);
    }
    __syncthreads();
#pragma unroll
    for (int k0 = 0; k0 < 64; k0 += 32) {
      bf16x8 a[4], b[JB];
#pragma unroll
      for (int i = 0; i < 4; i++) {
        int ra = wm + i * 16 + l15;
        int ba = ra * 8 + (((k0 >> 3) + q4) ^ (ra & 7));
        a[i] = *(const bf16x8*)&As[ba * 8];
      }
#pragma unroll
      for (int j = 0; j < JB; j++) {
        int rb = wn + j * 16 + l15;
        int bb = rb * 8 + (((k0 >> 3) + q4) ^ (rb & 7));
        b[j] = *(const bf16x8*)&Bs[bb * 8];
      }
#pragma unroll
      for (int i = 0; i < 4; i++)
#pragma unroll
        for (int j = 0; j < JB; j++)
          acc[i][j] = __builtin_amdgcn_mfma_f32_16x16x32_bf16(a[i], b[j], acc[i][j], 0, 0, 0);
    }
  }

  float bcol[JB];
#pragma unroll
  for (int j = 0; j < JB; j++) bcol[j] = bias[n_blk + wn + j * 16 + l15];
#pragma unroll
  for (int i = 0; i < 4; i++)
#pragma unroll
    for (int j = 0; j < JB; j++) {
      int col = n_blk + wn + j * 16 + l15;
#pragma unroll
      for (int r = 0; r < 4; r++) {
        int row = m_blk + wm + i * 16 + q4 * 4 + r;
        float v = acc[i][j][r] + bcol[j];
        size_t idx = (size_t)row * N + col;
        if (DYN && !isbf) ((float*)Cout)[idx] = v;
        else              ((__bf16*)Cout)[idx] = (__bf16)v;
      }
    }
}

// ---------------- LN + RoPE + V-transpose (fused) ----------------
__global__ __launch_bounds__(256) void ln_rope_v(const __bf16* __restrict__ qkv,
                                                 const void* __restrict__ rcos,
                                                 const void* __restrict__ rsin,
                                                 const void* __restrict__ qw,
                                                 const void* __restrict__ qb,
                                                 const void* __restrict__ kw,
                                                 const void* __restrict__ kb_,
                                                 const unsigned short* __restrict__ xdet,
                                                 __bf16* __restrict__ Qp,
                                                 __bf16* __restrict__ Kp,
                                                 __bf16* __restrict__ Vt) {
  __shared__ __bf16 vt[64][68];
  const int isbf = detect_isbf(xdet);
  const int tid = threadIdx.x, w = tid >> 6, lane = tid & 63;
  const int bh = blockIdx.y, h = bh & 15, b = bh >> 4;
  const int n0 = blockIdx.x * 64;

  float gq = ldf(qw, lane, isbf), bq_ = ldf(qb, lane, isbf);
  float gk = ldf(kw, lane, isbf), bk_ = ldf(kb_, lane, isbf);

#pragma unroll 2
  for (int t = 0; t < 16; t++) {
    const int n = n0 + w * 16 + t;
    const size_t tok = (size_t)b * 2048 + n;
    const __bf16* base = qkv + tok * 3072 + h * 192;
    float qv = (float)base[lane], kv = (float)base[64 + lane], vv = (float)base[128 + lane];

    float sq = qv, sk = kv;
#pragma unroll
    for (int m = 1; m < 64; m <<= 1) { sq += __shfl_xor(sq, m, 64); sk += __shfl_xor(sk, m, 64); }
    float muq = sq * (1.0f / 64.0f), muk = sk * (1.0f / 64.0f);
    float tq = qv - muq, tk = kv - muk;
    float vq = tq * tq, vk = tk * tk;
#pragma unroll
    for (int m = 1; m < 64; m <<= 1) { vq += __shfl_xor(vq, m, 64); vk += __shfl_xor(vk, m, 64); }
    float rsq = rsqrtf(vq * (1.0f / 64.0f) + 1e-6f);
    float rsk = rsqrtf(vk * (1.0f / 64.0f) + 1e-6f);
    float qn = tq * rsq * gq + bq_;
    float kn = tk * rsk * gk + bk_;

    float c = ldf(rcos, tok * 64 + lane, isbf), s = ldf(rsin, tok * 64 + lane, isbf);
    float qpart = __shfl_xor(qn, 32, 64), kpart = __shfl_xor(kn, 32, 64);
    float qrh = (lane < 32) ? -qpart : qpart;
    float krh = (lane < 32) ? -kpart : kpart;

    const size_t oidx = ((size_t)bh * 2048 + n) * 64 + lane;
    Qp[oidx] = (__bf16)((qn * c + qrh * s) * 0.1803368801111204f);  // 0.125 * log2(e)
    Kp[oidx] = (__bf16)(kn * c + krh * s);
    vt[lane][w * 16 + t] = (__bf16)vv;
  }
  __syncthreads();
  const int row = tid >> 2, qt = tid & 3;
  size_t gbase = (size_t)bh * 64 * 2048 + (size_t)row * 2048 + n0 + qt * 16;
#pragma unroll
  for (int u = 0; u < 4; u++)
    *(uint2*)&Vt[gbase + u * 4] = *(const uint2*)&vt[row][qt * 16 + u * 4];
}

// ---------------- flash attention: K-split x2, KT=32, XCD-swizzled grid ----------------
// Linear grid 1024; decode so all 16 q-blocks of one (bh,split) group share an XCD
// (id % 8 == XCD round-robin heuristic): id = ((g>>3)*16 + qblk)*8 + (g&7).
// Each XCD then streams only 8 K/V pairs (2 MB) -> fits its 4 MB L2.
// fp32 partial O; l via ones-row MFMA; no-max softmax; P truncate-packed via v_perm.
__global__ __launch_bounds__(256, 4) void attn(const __bf16* __restrict__ Qp,
                                               const __bf16* __restrict__ Kp,
                                               const __bf16* __restrict__ Vt,
                                               float* __restrict__ O0,
                                               float* __restrict__ O1,
                                               float* __restrict__ lpart) {
  __shared__ __align__(16) __bf16 sK[2][2048];   // [buf][(g=ks*2+c)*64+lane]*8
  __shared__ __align__(16) __bf16 sV[2][2048];   // [buf][(ds*64+lane)]*8
  __shared__ __align__(16) __bf16 sP[4][1024];   // per-wave, B-frag order (32q x 32k)

  const int tid = threadIdx.x, wid = tid >> 6, lane = tid & 63;
  const int q4 = lane >> 4, l15 = lane & 15;
  // XCD-locality decode
  const int lin = blockIdx.x;
  const int xcd = lin & 7;
  const int rest = lin >> 3;
  const int qblk = rest & 15;
  const int g = (rest >> 4) * 8 + xcd;   // 0..63
  const int bh = g & 31, split = g >> 5;
  const int q0w = qblk * 128 + wid * 32;
  const int kt0 = split * 1024;
  const __bf16* Qb = Qp + (size_t)bh * 2048 * 64;
  const __bf16* Kb = Kp + (size_t)bh * 2048 * 64;
  const __bf16* Vb = Vt + (size_t)bh * 64 * 2048;
  float* Op = split ? O1 : O0;
  __bf16* sPw = &sP[wid][0];
  const int pbase = (q4 >> 1) * 128 + l15 * 8 + (q4 & 1) * 4;

  // Q fragments (B-operand): B[q=l15][k=q4*8+j], 2 chains of 32 d
  bf16x8 qf[2][2];
#pragma unroll
  for (int qs = 0; qs < 2; qs++)
#pragma unroll
    for (int c = 0; c < 2; c++)
      qf[qs][c] = *(const bf16x8*)&Qb[(size_t)(q0w + qs * 16 + l15) * 64 + c * 32 + q4 * 8];

  // all-ones A-fragment -> l row sums on the matrix pipe
  bf16x8 ones8;
#pragma unroll
  for (int i = 0; i < 8; i++) ones8[i] = (__bf16)1.0f;

  f32x4 o[2][4] = {};
  f32x4 l_acc[2] = {};

#define STAGE(kt, bf)                                                                    \
  do {                                                                                   \
    async_copy16(Kb + (size_t)((kt) + (wid >> 1) * 16 + l15) * 64 + (wid & 1) * 32 + q4 * 8, \
                 &sK[bf][wid * 512]);                                                    \
    async_copy16(Vb + (size_t)(wid * 16 + l15) * 2048 + (kt) + q4 * 8,                   \
                 &sV[bf][wid * 512]);                                                    \
  } while (0)

  STAGE(kt0, 0);

  for (int it = 0; it < 32; ++it) {
    const int buf = it & 1;
    __syncthreads();  // readers of buf^1 done + loads into buf landed
    if (it < 31) STAGE(kt0 + (it + 1) * 32, buf ^ 1);

    // ---- QK^T (S^T): A = K rows (2 ks-subs), B = Q (2 q-subs), 2 d-chains ----
    bf16x8 ak[2][2];
#pragma unroll
    for (int ks = 0; ks < 2; ks++)
#pragma unroll
      for (int c = 0; c < 2; c++)
        ak[ks][c] = *(const bf16x8*)&sK[buf][((ks * 2 + c) * 64 + lane) * 8];
    f32x4 sc[2][2];
#pragma unroll
    for (int qs = 0; qs < 2; qs++)
#pragma unroll
      for (int ks = 0; ks < 2; ks++) {
        f32x4 z = {0.f, 0.f, 0.f, 0.f};
        z = __builtin_amdgcn_mfma_f32_16x16x32_bf16(ak[ks][0], qf[qs][0], z, 0, 0, 0);
        z = __builtin_amdgcn_mfma_f32_16x16x32_bf16(ak[ks][1], qf[qs][1], z, 0, 0, 0);
        sc[qs][ks] = z;
      }

    // ---- no-max softmax: p = exp2(s); truncate-pack to bf16 via v_perm ----
#pragma unroll
    for (int qs = 0; qs < 2; qs++)
#pragma unroll
      for (int ks = 0; ks < 2; ks++) {
        uint2 pk;
        {
          float p0 = __builtin_amdgcn_exp2f(sc[qs][ks][0]);
          float p1 = __builtin_amdgcn_exp2f(sc[qs][ks][1]);
          pk.x = __builtin_amdgcn_perm(__builtin_bit_cast(unsigned int, p1),
                                       __builtin_bit_cast(unsigned int, p0), 0x07060302u);
          float p2 = __builtin_amdgcn_exp2f(sc[qs][ks][2]);
          float p3 = __builtin_amdgcn_exp2f(sc[qs][ks][3]);
          pk.y = __builtin_amdgcn_perm(__builtin_bit_cast(unsigned int, p3),
                                       __builtin_bit_cast(unsigned int, p2), 0x07060302u);
        }
        *(uint2*)&sPw[qs * 512 + ks * 256 + pbase] = pk;
      }
    asm volatile("s_waitcnt lgkmcnt(0)" ::: "memory");  // P writes -> reads (same wave)

    // ---- PV (O^T += V^T.P) + l += ones.P on the matrix pipe ----
    bf16x8 pb[2];
#pragma unroll
    for (int qs = 0; qs < 2; qs++)
      pb[qs] = *(const bf16x8*)&sPw[(qs * 64 + lane) * 8];
#pragma unroll
    for (int qs = 0; qs < 2; qs++)
      l_acc[qs] = __builtin_amdgcn_mfma_f32_16x16x32_bf16(ones8, pb[qs], l_acc[qs], 0, 0, 0);
#pragma unroll
    for (int ds = 0; ds < 4; ds++) {
      bf16x8 av = *(const bf16x8*)&sV[buf][(ds * 64 + lane) * 8];
#pragma unroll
      for (int qs = 0; qs < 2; qs++)
        o[qs][ds] = __builtin_amdgcn_mfma_f32_16x16x32_bf16(av, pb[qs], o[qs][ds], 0, 0, 0);
    }
  }
#undef STAGE

  // ---- epilogue: fp32 partial O ([bh][q][d]) and fp32 partial l ----
#pragma unroll
  for (int qs = 0; qs < 2; qs++) {
    const int q = q0w + qs * 16 + l15;
    if (q4 == 0) lpart[(size_t)(split * 32 + bh) * 2048 + q] = l_acc[qs][0];
    size_t base = ((size_t)bh * 2048 + q) * 64;
#pragma unroll
    for (int ds = 0; ds < 4; ds++)
      *(f32x4*)&Op[base + ds * 16 + q4 * 4] = o[qs][ds];
  }
}

// ---------------- combine: Obuf = (O0+O1) / (l0+l1), bf16 [b][q][h*64+d] ----------------
__global__ __launch_bounds__(256) void combine(const float* __restrict__ O0,
                                               const float* __restrict__ O1,
                                               const float* __restrict__ lpart,
                                               __bf16* __restrict__ Obuf) {
  const int idx = blockIdx.x * 256 + threadIdx.x;  // 1,048,576 threads x 4 d
  const int d4 = idx & 15, q = (idx >> 4) & 2047, bh = idx >> 15;
  const int b = bh >> 4, h = bh & 15;
  const size_t po = ((size_t)bh * 2048 + q) * 64 + d4 * 4;
  f32x4 a = *(const f32x4*)&O0[po];
  f32x4 c = *(const f32x4*)&O1[po];
  float l = lpart[(size_t)bh * 2048 + q] + lpart[(size_t)(32 + bh) * 2048 + q];
  float rl = 1.0f / l;
  union { __bf16 h4[4]; uint2 u; } pk;
#pragma unroll
  for (int r = 0; r < 4; r++) pk.h4[r] = (__bf16)((a[r] + c[r]) * rl);
  *(uint2*)&Obuf[((size_t)(b * 2048 + q)) * 1024 + h * 64 + d4 * 4] = pk.u;
}

extern "C" void kernel_launch(void* const* d_in, const int* in_sizes, int n_in,
                              void* d_out, int out_size, void* d_ws, size_t ws_size,
                              hipStream_t stream) {
  const void* x   = d_in[0];
  const void* rc  = d_in[1];
  const void* rs  = d_in[2];
  const void* Wq  = d_in[3];
  const void* bq  = d_in[4];
  const void* Wk  = d_in[5];
  const void* bk  = d_in[6];
  const void* Wv  = d_in[7];
  const void* bv  = d_in[8];
  const void* qnw = d_in[9];
  const void* qnb = d_in[10];
  const void* knw = d_in[11];
  const void* knb = d_in[12];
  const void* Wo  = d_in[13];
  const void* bo  = d_in[14];
  const unsigned short* xdet = (const unsigned short*)x;

  // temporal aliasing plan (round-8 proven):
  //  [0, 25165824)        qkv bf16 (gemm0 -> ln_rope_v), then O0/O1 fp32 (attn -> combine)
  //  [25165824, 33554432) x_bf (prep -> gemm0, fp32 path only; dead before attn)
  //  [33554432, 41943040) Qp (ln_rope_v -> attn), then Obuf (combine -> gemm1)
  char* ws = (char*)d_ws;
  __bf16* qkv   = (__bf16*)ws;
  float*  O0    = (float*)ws;                 // 16 MB
  float*  O1    = (float*)(ws + 16777216);    // 16 MB
  __bf16* x_bf  = (__bf16*)(ws + 25165824);
  __bf16* Qp    = (__bf16*)(ws + 33554432);
  __bf16* Obuf  = (__bf16*)(ws + 33554432);
  __bf16* Kp    = (__bf16*)(ws + 41943040);
  __bf16* Vt    = (__bf16*)(ws + 50331648);
  __bf16* Wt    = (__bf16*)(ws + 58720256);   // [3072][1024] 6 MB
  __bf16* Wot   = (__bf16*)(ws + 65011712);   // [1024][1024] 2 MB
  float*  bias  = (float*)(ws + 67108864);    // [4096]
  float*  lprt  = (float*)(ws + 67125248);    // [2][32][2048] fp32, 512 KB

  prep<<<dim3(32, 32, 5), 256, 0, stream>>>(Wq, Wk, Wv, Wo, x, bq, bk, bv, bo,
                                            Wt, Wot, x_bf, bias);
  gemm_bt<0, 128, 1><<<dim3(32, 24), 256, 0, stream>>>(x_bf, (const __bf16*)x, Wt, bias,
                                                       qkv, xdet, 4096, 3072, 1024);
  ln_rope_v<<<dim3(32, 32), 256, 0, stream>>>(qkv, rc, rs, qnw, qnb, knw, knb, xdet,
                                              Qp, Kp, Vt);
  attn<<<1024, 256, 0, stream>>>(Qp, Kp, Vt, O0, O1, lprt);
  combine<<<4096, 256, 0, stream>>>(O0, O1, lprt, Obuf);
  gemm_bt<1, 64, 0><<<dim3(32, 16), 256, 0, stream>>>(Obuf, nullptr, Wot, bias + 3072,
                                                      d_out, xdet, 4096, 1024, 1024);
}